// Round 9
// baseline (360.720 us; speedup 1.0000x reference)
//
#include <hip/hip_runtime.h>
#include <math.h>

#define NTHR 256
#define K1_BLKS 64
#define INV_SQRT_D 0.04419417382415922f
#define MAGIC 0x5ca1ab1eu

// ws float offsets
#define O_POS   0         // 2178
#define O_VC    2304      // 1024  v-const (kvx_v + b_kvx_v + b_kvb_v)
#define O_QV    3328      // 1024  q-projection of x
#define O_W     4352      // 50    attention feature weights
#define O_KB    4416      // 38    K_i^T @ bq_i
#define O_CFIN  4480      // 512
#define O_R     4992      // 2*512*25  W_fin,h @ Wv_h
#define O_S     30592     // 2*512*25  W_sec @ R_h
#define O_U     56192     // 2*19*512  K_i^T @ Wq_i
#define O_VP    75648     // 2*19*512  U_i @ W_sec
#define O_P     95104     // 2*19*51   folded policy matrices
#define O_PC    97042     // 242
#define O_BAR   97536     // 2 phases * 64 blocks * 32 uints

// relaxed agent-scope atomics: sc0/sc1 cache-bypassing accesses -> coherent at IF$,
// no wbl2/inv fences ever emitted.
__device__ __forceinline__ void st_ws(float* p, float v) {
    __hip_atomic_store(p, v, __ATOMIC_RELAXED, __HIP_MEMORY_SCOPE_AGENT);
}
__device__ __forceinline__ float ld_ws(const float* p) {
    return __hip_atomic_load(p, __ATOMIC_RELAXED, __HIP_MEMORY_SCOPE_AGENT);
}

__device__ __forceinline__ void gridbar(unsigned* bar, int phase, int blk) {
    __syncthreads();
    asm volatile("s_waitcnt vmcnt(0) lgkmcnt(0)" ::: "memory");  // data stores complete
    if (threadIdx.x == 0)
        __hip_atomic_store(&bar[phase * 2048 + blk * 32], MAGIC,
                           __ATOMIC_RELAXED, __HIP_MEMORY_SCOPE_AGENT);
    if (threadIdx.x < K1_BLKS) {
        unsigned* f = &bar[phase * 2048 + threadIdx.x * 32];
        int spins = 0;
        while (__hip_atomic_load(f, __ATOMIC_RELAXED, __HIP_MEMORY_SCOPE_AGENT) != MAGIC) {
            __builtin_amdgcn_s_sleep(1);
            if (++spins > 300000) break;   // bounded: no hang
        }
    }
    asm volatile("" ::: "memory");
    __syncthreads();
}

__global__ __launch_bounds__(NTHR) void k1_fold(
    const float* __restrict__ b_first,
    const float* __restrict__ W_kvx, const float* __restrict__ b_kvx,
    const float* __restrict__ W_kvb, const float* __restrict__ b_kvb,
    const float* __restrict__ W_q, const float* __restrict__ b_q,
    const float* __restrict__ W_fin, const float* __restrict__ b_fin,
    const float* __restrict__ W_sec, const float* __restrict__ b_sec,
    const float* __restrict__ W0_kp, const float* __restrict__ b0_kp,
    const float* __restrict__ W0_q, const float* __restrict__ b0_q,
    const float* __restrict__ W1_kp, const float* __restrict__ b1_kp,
    const float* __restrict__ W1_q, const float* __restrict__ b1_q,
    float* __restrict__ ws)
{
    __shared__ float sh[12800];   // 51.2 KB: S-stage R tile / U-stage Klds / GEMV x
    unsigned* bar = (unsigned*)(ws + O_BAR);
    int blk = blockIdx.x, t = threadIdx.x, wv = t >> 6, lane = t & 63;

    // ================= STAGE 1 =================
    if (blk < 32) {                       // R_h[c,f] = sum_d W_fin[c,h*512+d]*Wv_h[d,f]
        int h = blk >> 4, c0 = (blk & 15) * 32;
        for (int oo = 0; oo < 4; oo++) {
            int o = t + oo * 256;
            if (o < 800) {
                int c = c0 + o / 25, f = o - (o / 25) * 25;
                const float* wf = W_fin + c * 1024 + h * 512;
                const float* wvp = W_kvb + (1024 + h * 512) * 25 + f;
                float acc = 0.f;
                #pragma unroll 8
                for (int d = 0; d < 512; d++) acc += wf[d] * wvp[d * 25];
                st_ws(ws + O_R + h * 12800 + c * 25 + f, acc);
            }
        }
    } else if (blk < 40) {                // U_i[r,c] = sum_d K_i[r,d]*Wq_i[d*512+c]
        int bb = blk - 32, i = bb >> 2, c0 = (bb & 3) * 128;
        const float* kpW = i ? W1_kp : W0_kp;
        const float* kpb = i ? b1_kp : b0_kp;
        const float* wq = i ? W1_q : W0_q;
        for (int idx = t; idx < 9216; idx += 256) {
            int d = idx / 18, j = idx - d * 18;
            sh[d * 20 + 1 + j] = kpW[idx];
        }
        for (int d = t; d < 512; d += 256) { sh[d * 20] = kpb[d]; sh[d * 20 + 19] = 0.f; }
        __syncthreads();
        int c = c0 + (t & 127), half = t >> 7;
        float acc[10];
        for (int k = 0; k < 10; k++) acc[k] = 0.f;
        #pragma unroll 4
        for (int d = 0; d < 512; d++) {
            float w = wq[d * 512 + c];
            #pragma unroll
            for (int k = 0; k < 10; k++) acc[k] += sh[d * 20 + half + 2 * k] * w;
        }
        for (int k = 0; k < 10; k++) {
            int r = half + 2 * k;
            if (r < 19) st_ws(ws + O_U + (i * 19 + r) * 512 + c, acc[k]);
        }
    } else if (blk < 56) {                // vc & qv GEMVs
        for (int d = t; d < 512; d += 256) sh[d] = fmaxf(b_first[d], 0.f);
        __syncthreads();
        int base = (blk - 40) * 128;
        for (int rr = 0; rr < 32; rr++) {
            int row = base + wv * 32 + rr;
            const float* R_; float bias; float* outp;
            if (row < 1024) {
                R_ = W_kvx + (1024 + row) * 512;
                bias = b_kvx[1024 + row] + b_kvb[1024 + row];
                outp = ws + O_VC + row;
            } else {
                int r2 = row - 1024;
                R_ = W_q + r2 * 512; bias = b_q[r2]; outp = ws + O_QV + r2;
            }
            float a = 0.f;
            #pragma unroll
            for (int d = lane; d < 512; d += 64) a += R_[d] * sh[d];
            for (int o = 32; o; o >>= 1) a += __shfl_xor(a, o, 64);
            if (lane == 0) st_ws(outp, a + bias);
        }
    } else if (blk == 56) {               // pos table
        for (int gid = t; gid < 2178; gid += 256) {
            int p = gid / 18, jj = gid - p * 18;
            int i = p / 11, j = p - i * 11;
            float r = (i - 5) * 0.2f, c = (j - 5) * 0.2f, z = 0.5f * (r + c);
            float xs3[3] = {r, c, z};
            float pp3[3] = {1.f, 2.f, 4.f};
            int sc = jj / 9, rem = jj - sc * 9, a = rem / 3, q = rem - a * 3;
            float ang = 6.283185307179586f * xs3[q] / pp3[a];
            st_ws(ws + O_POS + gid, sc ? sinf(ang) : cosf(ang));
        }
    } else if (blk == 57) {               // kb_i = K_i^T @ bq_i
        for (int o = wv; o < 38; o += 4) {
            int pol = o / 19, r = o - pol * 19;
            const float* kpW = pol ? W1_kp : W0_kp;
            const float* kpb = pol ? b1_kp : b0_kp;
            const float* bq = pol ? b1_q : b0_q;
            float a = 0.f;
            for (int d = lane; d < 512; d += 64)
                a += ((r == 0) ? kpb[d] : kpW[d * 18 + r - 1]) * bq[d];
            for (int o2 = 32; o2; o2 >>= 1) a += __shfl_xor(a, o2, 64);
            if (lane == 0) st_ws(ws + O_KB + o, a);
        }
    }
    gridbar(bar, 0, blk);

    // ================= STAGE 2 =================
    if (blk < 32) {                       // S_h = W_sec @ R_h   (R staged to LDS)
        int h = blk >> 4, c0 = (blk & 15) * 32;
        for (int idx = t; idx < 12800; idx += 256) sh[idx] = ld_ws(ws + O_R + h * 12800 + idx);
        __syncthreads();
        for (int oo = 0; oo < 4; oo++) {
            int o = t + oo * 256;
            if (o < 800) {
                int c = c0 + o / 25, f = o - (o / 25) * 25;
                const float* wsec = W_sec + c * 512;
                float acc = 0.f;
                #pragma unroll 8
                for (int e = 0; e < 512; e++) acc += wsec[e] * sh[e * 25 + f];
                st_ws(ws + O_S + h * 12800 + c * 25 + f, acc);
            }
        }
    } else if (blk < 40) {                // V'_i = U_i @ W_sec
        int bb = blk - 32, i = bb >> 2, c0 = (bb & 3) * 128;
        int c = c0 + (t & 127), half = t >> 7;
        const float* up = ws + O_U + i * 19 * 512;
        float acc[10];
        for (int k = 0; k < 10; k++) acc[k] = 0.f;
        #pragma unroll 2
        for (int e = 0; e < 512; e++) {
            float w = W_sec[e * 512 + c];
            #pragma unroll
            for (int k = 0; k < 10; k++) {
                int r = half + 2 * k;
                float uv = (r < 19) ? ld_ws(up + r * 512 + e) : 0.f;
                acc[k] += uv * w;
            }
        }
        for (int k = 0; k < 10; k++) {
            int r = half + 2 * k;
            if (r < 19) st_ws(ws + O_VP + (i * 19 + r) * 512 + c, acc[k]);
        }
    } else if (blk < 48) {                // cfin = W_fin @ vc + b_fin
        int base = (blk - 40) * 64;
        for (int rr = 0; rr < 16; rr++) {
            int row = base + wv * 16 + rr;
            const float* wf = W_fin + row * 1024;
            float a = 0.f;
            #pragma unroll
            for (int d = lane; d < 1024; d += 64) a += wf[d] * ld_ws(ws + O_VC + d);
            for (int o = 32; o; o >>= 1) a += __shfl_xor(a, o, 64);
            if (lane == 0) st_ws(ws + O_CFIN + row, a + b_fin[row]);
        }
    } else if (blk == 48) {               // w_h = qv_h^T @ Wk_h
        for (int o = wv; o < 50; o += 4) {
            int h = o / 25, j = o - h * 25;
            float a = 0.f;
            for (int d = lane; d < 512; d += 64)
                a += W_kvb[(h * 512 + d) * 25 + j] * ld_ws(ws + O_QV + h * 512 + d);
            for (int o2 = 32; o2; o2 >>= 1) a += __shfl_xor(a, o2, 64);
            if (lane == 0) st_ws(ws + O_W + o, a);
        }
    }
    gridbar(bar, 1, blk);

    // ================= STAGE 3 (final outputs: normal stores; K2 reads across kernel boundary)
    if (blk < 4) {                        // P cols 1..50 = U_i @ S_h  (S staged to LDS)
        int i = blk >> 1, h = blk & 1;
        for (int idx = t; idx < 12800; idx += 256) sh[idx] = ld_ws(ws + O_S + h * 12800 + idx);
        __syncthreads();
        for (int oo = 0; oo < 2; oo++) {
            int o = t + oo * 256;
            if (o < 475) {
                int r = o / 25, f = o - r * 25;
                const float* up = ws + O_U + (i * 19 + r) * 512;
                float acc = 0.f;
                #pragma unroll 8
                for (int c = 0; c < 512; c++) acc += ld_ws(up + c) * sh[c * 25 + f];
                ws[O_P + i * 969 + r * 51 + 1 + h * 25 + f] = acc;
            }
        }
    } else if (blk == 4) {                // col0 = V'@cfin + U@b_sec + kb
        for (int o = wv; o < 38; o += 4) {
            int pol = o / 19, r = o - pol * 19;
            const float* vp = ws + O_VP + (pol * 19 + r) * 512;
            const float* up = ws + O_U + (pol * 19 + r) * 512;
            float a = 0.f;
            for (int c = lane; c < 512; c += 64)
                a += ld_ws(vp + c) * ld_ws(ws + O_CFIN + c) + ld_ws(up + c) * b_sec[c];
            for (int o2 = 32; o2; o2 >>= 1) a += __shfl_xor(a, o2, 64);
            if (lane == 0) ws[O_P + pol * 969 + r * 51] = a + ld_ws(ws + O_KB + o);
        }
    } else if (blk == 5) {                // pc
        if (t < 242) {
            int h = t / 121, p = t - h * 121;
            float a = 0.f;
            for (int j = 0; j < 18; j++)
                a += ld_ws(ws + O_W + h * 25 + 7 + j) * ld_ws(ws + O_POS + p * 18 + j);
            ws[O_PC + h * 121 + p] = a;
        }
    }
}

// ---------------- K2: per-batch main (barrier-free) ----------------
__device__ __forceinline__ float blkmax(float v, volatile float* tmp) {
    for (int o = 32; o; o >>= 1) v = fmaxf(v, __shfl_xor(v, o, 64));
    __syncthreads();
    if ((threadIdx.x & 63) == 0) tmp[threadIdx.x >> 6] = v;
    __syncthreads();
    float r = fmaxf(fmaxf(tmp[0], tmp[1]), fmaxf(tmp[2], tmp[3]));
    __syncthreads();
    return r;
}
__device__ __forceinline__ float blksum(float v, volatile float* tmp) {
    for (int o = 32; o; o >>= 1) v += __shfl_xor(v, o, 64);
    __syncthreads();
    if ((threadIdx.x & 63) == 0) tmp[threadIdx.x >> 6] = v;
    __syncthreads();
    float r = tmp[0] + tmp[1] + tmp[2] + tmp[3];
    __syncthreads();
    return r;
}

__global__ __launch_bounds__(NTHR) void k2_main(const float* __restrict__ obs,
                                                const float* __restrict__ ws,
                                                float* __restrict__ out) {
    __shared__ float sgl[121];
    __shared__ float nbs[121 * 7];
    __shared__ float att[121];
    __shared__ float bbar[50];
    __shared__ float cvec[19];
    __shared__ float tmp[4];
    int b = blockIdx.x, t = threadIdx.x;
    if (t < 121) sgl[t] = obs[(b * 121 + t) * 2] - obs[(b * 121 + t) * 2 + 1];
    __syncthreads();
    float dots[2];
    if (t < 121) {
        const int DRo[7] = {-1, -1, 0, 0, 0, -1, -1};
        const int DCo[7] = {0, 1, -1, 0, 1, -1, 0};
        int i = t / 11, j = t - i * 11;
        float nb[7];
        for (int k = 0; k < 7; k++) {
            int ii = i + DRo[k], jj = j + DCo[k];
            float v = (ii >= 0 && ii < 11 && jj >= 0 && jj < 11) ? sgl[ii * 11 + jj] : 0.f;
            nb[k] = v; nbs[t * 7 + k] = v;
        }
        for (int h = 0; h < 2; h++) {
            float acc = ws[O_PC + h * 121 + t];
            for (int k = 0; k < 7; k++) acc += ws[O_W + h * 25 + k] * nb[k];
            dots[h] = acc * INV_SQRT_D;
        }
    } else { dots[0] = dots[1] = -INFINITY; }
    for (int h = 0; h < 2; h++) {
        float m = blkmax(dots[h], tmp);
        float e = (t < 121) ? expf(dots[h] - m) : 0.f;
        float s = blksum(e, tmp);
        if (t < 121) att[t] = e / s;
        __syncthreads();
        if (t < 25) {
            float acc = 0.f;
            if (t < 7) { for (int p = 0; p < 121; p++) acc += att[p] * nbs[p * 7 + t]; }
            else { int j = t - 7; for (int p = 0; p < 121; p++) acc += att[p] * ws[O_POS + p * 18 + j]; }
            bbar[h * 25 + t] = acc;
        }
        __syncthreads();
    }
    for (int pol = 0; pol < 2; pol++) {
        if (t < 19) {
            const float* Pr = ws + O_P + pol * 969 + t * 51;
            float a = Pr[0];
            for (int c = 1; c < 51; c++) a += Pr[c] * bbar[c - 1];
            cvec[t] = a;
        }
        __syncthreads();
        float d;
        if (t < 121) {
            d = cvec[0];
            for (int j = 0; j < 18; j++) d += ws[O_POS + t * 18 + j] * cvec[1 + j];
            d *= INV_SQRT_D;
        } else d = -INFINITY;
        float m = blkmax(d, tmp);
        float e = (t < 121) ? expf(d - m) : 0.f;
        float s = blksum(e, tmp);
        float ls = logf(s);
        if (t < 121) out[pol * 61952 + b * 121 + t] = d - m - ls;
        __syncthreads();
    }
}

extern "C" void kernel_launch(void* const* d_in, const int* in_sizes, int n_in,
                              void* d_out, int out_size, void* d_ws, size_t ws_size,
                              hipStream_t stream) {
    const float* obs     = (const float*)d_in[0];
    const float* b_first = (const float*)d_in[2];
    const float* W_kvx   = (const float*)d_in[3];
    const float* b_kvx   = (const float*)d_in[4];
    const float* W_kvb   = (const float*)d_in[5];
    const float* b_kvb   = (const float*)d_in[6];
    const float* W_q     = (const float*)d_in[7];
    const float* b_q     = (const float*)d_in[8];
    const float* W_fin   = (const float*)d_in[9];
    const float* b_fin   = (const float*)d_in[10];
    const float* W_sec   = (const float*)d_in[11];
    const float* b_sec   = (const float*)d_in[12];
    const float* W0_kp   = (const float*)d_in[13];
    const float* b0_kp   = (const float*)d_in[14];
    const float* W0_q    = (const float*)d_in[17];
    const float* b0_q    = (const float*)d_in[18];
    const float* W1_kp   = (const float*)d_in[19];
    const float* b1_kp   = (const float*)d_in[20];
    const float* W1_q    = (const float*)d_in[23];
    const float* b1_q    = (const float*)d_in[24];
    float* ws = (float*)d_ws;
    float* out = (float*)d_out;

    hipLaunchKernelGGL(k1_fold, dim3(K1_BLKS), dim3(NTHR), 0, stream,
                       b_first, W_kvx, b_kvx, W_kvb, b_kvb, W_q, b_q,
                       W_fin, b_fin, W_sec, b_sec,
                       W0_kp, b0_kp, W0_q, b0_q, W1_kp, b1_kp, W1_q, b1_q, ws);
    hipLaunchKernelGGL(k2_main, dim3(512), dim3(NTHR), 0, stream, obs, ws, out);
}